// Round 5
// baseline (165.239 us; speedup 1.0000x reference)
//
#include <hip/hip_runtime.h>

// GroupNorm(32) -> phi 1x1 -> soft-VQ softmax vs codebook -> wz 1x1 + residual. fp32 I/O.
// x:(10,64,128,128), mb:(64,512), phi_w/wz_w:(64,64). B=10, C=64, HW=16384, K=512.
//
// R14: 32x32 MFMA (R12's LDS-pipe-diet theory) WITHOUT permlane. R12/R13's inline-asm
// v_permlane32_swap failed both operand orders with inconsistent failure modes (0.56 vs
// NaN from a pure routing change) -> compiler/asm interaction, not layout. This version
// keeps the halved per-token A-frag traffic of mfma_f32_32x32x16_bf16 (16B/lane serves
// 32 cols) and does the C->B-frag conversion via the R11-verified per-wave LDS
// round-trip: ET[tok][entry], stride-72 rows, scatter by C/D map
// row=(reg&3)+8*(reg>>2)+4*hl, col=lane&31 (HW-verified m74/m101), gather b128 by
// B-frag map k=hl*8+j. No cross-lane ops anywhere.
//  - 256-thr blocks, 4 waves x 32 tokens = 128 tokens/block, 1280 blocks.
//  - Frag staging identical to R11/R12: global_load_lds, contiguous 16KB chunks
//    (mbA 8K + mbY 8K), double-buffered, one barrier per chunk.
//  - LDS 51.2KB (Fg 32K + ET 18.4K) -> 3 blocks/CU = 12 waves/CU (R11 residency),
//    but per-token LDS ops ~halved vs R11.
//
// ws (ushort):
//  [0    ..32768) mbA  score A-frags ((cc*2+u)*4+ks)*512+lane*8+j
//                      = mb[(ks*16+hl*8+j)*512 + cc*64+u*32+col]   (col=lane&31,hl=lane>>5)
//  [32768..65536) mbY  Y A-frags ((cc*2+t)*4+ks)*512+lane*8+j
//                      = mb[(t*32+col)*512 + cc*64+ks*16+hl*8+j]
//  [65536..69632) phiA (t*4+ks)*512+lane*8+j = phi_w[(t*32+col)*64 + ks*16+hl*8+j]
//  [69632..73728) wzA  same for wz_w
//  float view at ushort 73728 (statf): [0..320) sum[b*32+g], [320..640) sumsq (atomic)

#define HWN 16384
#define CCH 64
#define PSC 0.18033688011112042f   // 0.125 * log2(e)
#define ETS 72                     // ET row stride (ushorts): 16B-aligned rows, 4-way bank cost

using short8 = __attribute__((ext_vector_type(8))) short;
using f32x4  = __attribute__((ext_vector_type(4))) float;
using f32x16 = __attribute__((ext_vector_type(16))) float;

__device__ __forceinline__ ushort f2bf(float f) {
    union { float f; unsigned int i; } v; v.f = f;
    return (ushort)((v.i + 0x8000u) >> 16);   // round-half-up
}
__device__ __forceinline__ unsigned int pk2(float a, float b) {
    union { float f; unsigned int i; } va, vb; va.f = a; vb.f = b;
    return __builtin_amdgcn_perm(vb.i + 0x8000u, va.i + 0x8000u, 0x07060302u);
}

// blocks [0, nstat): GroupNorm partial sums, 8 parts per (b,g), atomicAdd into statf.
// blocks [nstat, nstat+288): weight prep gathers (32x32 A-frag layouts).
__global__ __launch_bounds__(256) void prep_stats_kernel(
    const float* __restrict__ x, const float* __restrict__ mb,
    const float* __restrict__ phiw, const float* __restrict__ wzw,
    ushort* __restrict__ ws, int nstat)
{
    if (blockIdx.x >= nstat) {
        int i = (blockIdx.x - nstat) * 256 + threadIdx.x;   // 0..73727
        int j = i & 7, lane = (i >> 3) & 63;
        int col = lane & 31, hl = lane >> 5;
        if (i < 32768) {
            int f = i >> 9, ks = f & 3, u = (f >> 2) & 1, cc = f >> 3;
            ws[i] = f2bf(mb[(ks * 16 + hl * 8 + j) * 512 + cc * 64 + u * 32 + col]);
        } else if (i < 65536) {
            int f = (i - 32768) >> 9, ks = f & 3, t = (f >> 2) & 1, cc = f >> 3;
            ws[i] = f2bf(mb[(t * 32 + col) * 512 + cc * 64 + ks * 16 + hl * 8 + j]);
        } else if (i < 69632) {
            int f = (i - 65536) >> 9, ks = f & 3, t = f >> 2;
            ws[i] = f2bf(phiw[(t * 32 + col) * 64 + ks * 16 + hl * 8 + j]);
        } else {
            int f = (i - 69632) >> 9, ks = f & 3, t = f >> 2;
            ws[i] = f2bf(wzw[(t * 32 + col) * 64 + ks * 16 + hl * 8 + j]);
        }
        return;
    }
    float* statf = (float*)(ws + 73728);
    int blk  = blockIdx.x;            // b*256 + g*8 + part
    int b    = blk >> 8;
    int g    = (blk >> 3) & 31;
    int part = blk & 7;
    const float4* b4 = (const float4*)(x + (size_t)b * CCH * HWN + (size_t)(g * 2) * HWN) + part * 1024;
    float s = 0.f, s2 = 0.f;
    for (int i = threadIdx.x; i < 1024; i += 256) {
        float4 u = b4[i];
        s  += (u.x + u.y) + (u.z + u.w);
        s2 += (u.x*u.x + u.y*u.y) + (u.z*u.z + u.w*u.w);
    }
    for (int off = 32; off > 0; off >>= 1) {
        s  += __shfl_down(s, off);
        s2 += __shfl_down(s2, off);
    }
    __shared__ float rs[4], rs2[4];
    int wave = threadIdx.x >> 6, lane = threadIdx.x & 63;
    if (lane == 0) { rs[wave] = s; rs2[wave] = s2; }
    __syncthreads();
    if (threadIdx.x == 0) {
        atomicAdd(&statf[b * 32 + g],       rs[0] + rs[1] + rs[2] + rs[3]);
        atomicAdd(&statf[320 + b * 32 + g], rs2[0] + rs2[1] + rs2[2] + rs2[3]);
    }
}

// Stage one 16KB frag chunk (mbA 8KB + mbY 8KB) into LDS, split across 4 waves.
// mbA chunk cc = ws bytes [cc*8192, +8192); mbY chunk cc = [65536 + cc*8192, +8192).
__device__ __forceinline__ void stage_chunk(const ushort* ws, ushort* fg,
                                            int cc, int wv, int lane) {
    const int r = wv >> 1, half = wv & 1;          // r: 0=mbA, 1=mbY
    const char* g = (const char*)ws + r * 65536 + cc * 8192 + half * 4096 + lane * 16;
    char* l = (char*)fg + r * 8192 + half * 4096;
#pragma unroll
    for (int k = 0; k < 4; ++k)
        __builtin_amdgcn_global_load_lds(
            (const __attribute__((address_space(1))) unsigned int*)(g + k * 1024),
            (__attribute__((address_space(3))) unsigned int*)(l + k * 1024),
            16, 0, 0);
}

__global__ __launch_bounds__(256, 3) void main_mfma(
    const float* __restrict__ x, const ushort* __restrict__ ws,
    const float* __restrict__ phib, const float* __restrict__ gnw,
    const float* __restrict__ gnb, const float* __restrict__ wzb,
    float* __restrict__ out)
{
    const int lane = threadIdx.x & 63, wv = threadIdx.x >> 6;
    const int col = lane & 31, hl = lane >> 5;
    const int blk = blockIdx.x;                       // 1280 blocks, 128 tokens each
    const int b   = blk >> 7;                         // 128 blocks per image
    const int hw0 = ((blk & 127) << 7) + (wv << 5);   // this wave's 32 tokens
    const int tok = hw0 + col;

    const ushort* phiA = ws + 65536;
    const ushort* wzA  = ws + 69632;
    const float*  statf = (const float*)(ws + 73728);

    __shared__ ushort Fg[2][8192];                    // frag staging: 2 x 16KB
    __shared__ ushort ET[4][32][ETS];                 // per-wave token-major scratch
    ushort* Ew = &ET[wv][col][0];                     // this lane's token row

    const float* xb = x + (size_t)b * CCH * HWN;

    // prologue: kick off chunk-0 frag staging; latency hides under GN+phi.
    stage_chunk(ws, &Fg[0][0], 0, wv, lane);

    // ---- stage 1: x -> GroupNorm (finalize from atomic sums) -> bf16 B-frags ----
    // bx[ks][j] = xn[c = ks*16 + hl*8 + j][tok]
    short8 bx[4];
#pragma unroll
    for (int ks = 0; ks < 4; ++ks) {
        const int cbase = ks * 16 + hl * 8;
        f32x4 sm4 = *(const f32x4*)(statf + b * 32 + (cbase >> 1));
        f32x4 sq4 = *(const f32x4*)(statf + 320 + b * 32 + (cbase >> 1));
        f32x4 mu4, rs4;
#pragma unroll
        for (int r = 0; r < 4; ++r) {
            mu4[r] = sm4[r] * (1.f / 32768.f);
            float var = sq4[r] * (1.f / 32768.f) - mu4[r] * mu4[r];
            rs4[r] = rsqrtf(var + 1e-6f);
        }
        f32x4 gwv0 = *(const f32x4*)(gnw + cbase), gwv1 = *(const f32x4*)(gnw + cbase + 4);
        f32x4 gbv0 = *(const f32x4*)(gnb + cbase), gbv1 = *(const f32x4*)(gnb + cbase + 4);
#pragma unroll
        for (int j = 0; j < 8; ++j) {
            float v  = xb[(size_t)(cbase + j) * HWN + tok];
            float gw = (j < 4) ? gwv0[j & 3] : gwv1[j & 3];
            float gb = (j < 4) ? gbv0[j & 3] : gbv1[j & 3];
            float xn = (v - mu4[j >> 1]) * rs4[j >> 1] * gw + gb;
            bx[ks][j] = (short)f2bf(xn);
        }
    }

    // ---- P^T = phi_w * xn (2 row-tiles); bias+PSC; ET roundtrip -> bp B-frags ----
#pragma unroll
    for (int t = 0; t < 2; ++t) {
        f32x16 P;
#pragma unroll
        for (int r = 0; r < 16; ++r) P[r] = 0.f;
#pragma unroll
        for (int ks = 0; ks < 4; ++ks) {
            short8 ap = *(const short8*)(phiA + (((t * 4 + ks) << 9) + (lane << 3)));
            P = __builtin_amdgcn_mfma_f32_32x32x16_bf16(ap, bx[ks], P, 0, 0, 0);
        }
        // C-reg w*4+r -> channel row t*32 + w*8 + hl*4 + r (within this lane's tok)
#pragma unroll
        for (int w = 0; w < 4; ++w) {
            f32x4 pb = *(const f32x4*)(phib + t * 32 + w * 8 + hl * 4);
            float v0 = (P[w*4+0] + pb[0]) * PSC, v1 = (P[w*4+1] + pb[1]) * PSC;
            float v2 = (P[w*4+2] + pb[2]) * PSC, v3 = (P[w*4+3] + pb[3]) * PSC;
            *(uint2*)(Ew + t * 32 + w * 8 + hl * 4) = make_uint2(pk2(v0, v1), pk2(v2, v3));
        }
    }
    short8 bp[4];
#pragma unroll
    for (int ks = 0; ks < 4; ++ks)
        bp[ks] = *(const short8*)(Ew + ks * 16 + hl * 8);   // k = hl*8+j -> channel

    // chunk-0 frags must be resident before anyone reads them
    __syncthreads();   // implicit vmcnt(0)+lgkmcnt(0) drain

    // ---- streaming softmax + Y over 8 chunks of 64 codebook entries ----
    f32x16 accY[2];
#pragma unroll
    for (int t = 0; t < 2; ++t)
#pragma unroll
        for (int r = 0; r < 16; ++r) accY[t][r] = 0.f;
    float lsum = 0.f;

    for (int cc = 0; cc < 8; ++cc) {
        if (cc < 7) stage_chunk(ws, &Fg[(cc + 1) & 1][0], cc + 1, wv, lane);
        const ushort* fA = &Fg[cc & 1][0];      // mbA chunk: [0..4096) ushorts
        const ushort* fY = fA + 4096;           // mbY chunk: [4096..8192)

#pragma unroll
        for (int u = 0; u < 2; ++u) {
            f32x16 S;
#pragma unroll
            for (int r = 0; r < 16; ++r) S[r] = 0.f;
#pragma unroll
            for (int ks = 0; ks < 4; ++ks) {
                short8 am = *(const short8*)(fA + (((u * 4 + ks) << 9) + (lane << 3)));
                S = __builtin_amdgcn_mfma_f32_32x32x16_bf16(am, bp[ks], S, 0, 0, 0);
            }
            float e[16];
#pragma unroll
            for (int r = 0; r < 16; ++r) e[r] = __builtin_exp2f(S[r]);
#pragma unroll
            for (int r = 0; r < 8; ++r) lsum += e[2*r] + e[2*r+1];
            // entry row = u*32 + w*8 + hl*4 + r
#pragma unroll
            for (int w = 0; w < 4; ++w)
                *(uint2*)(Ew + u * 32 + w * 8 + hl * 4) =
                    make_uint2(pk2(e[4*w+0], e[4*w+1]), pk2(e[4*w+2], e[4*w+3]));
        }
        short8 be[4];
#pragma unroll
        for (int ks = 0; ks < 4; ++ks)
            be[ks] = *(const short8*)(Ew + ks * 16 + hl * 8);   // k = entry ks*16+hl*8+j
#pragma unroll
        for (int t = 0; t < 2; ++t)
#pragma unroll
            for (int ks = 0; ks < 4; ++ks) {
                short8 ay = *(const short8*)(fY + (((t * 4 + ks) << 9) + (lane << 3)));
                accY[t] = __builtin_amdgcn_mfma_f32_32x32x16_bf16(ay, be[ks], accY[t], 0, 0, 0);
            }
        // next-chunk staging must land and all waves must be done with fA/fY
        __syncthreads();   // implicit vmcnt(0) drain (covered by this chunk's compute)
    }

    // softmax denominator: lanes l and l+32 share a token; fold hl halves.
    lsum += __shfl_xor(lsum, 32);
    const float linv = 1.f / lsum;

    // ---- Y -> ET roundtrip -> by B-frags, then Out^T = wz * Y ----
#pragma unroll
    for (int t = 0; t < 2; ++t)
#pragma unroll
        for (int w = 0; w < 4; ++w)
            *(uint2*)(Ew + t * 32 + w * 8 + hl * 4) =
                make_uint2(pk2(accY[t][4*w+0], accY[t][4*w+1]),
                           pk2(accY[t][4*w+2], accY[t][4*w+3]));
    short8 by[4];
#pragma unroll
    for (int ks = 0; ks < 4; ++ks)
        by[ks] = *(const short8*)(Ew + ks * 16 + hl * 8);

    float* ob = out + (size_t)b * CCH * HWN;
#pragma unroll
    for (int t = 0; t < 2; ++t) {
        f32x16 C;
#pragma unroll
        for (int r = 0; r < 16; ++r) C[r] = 0.f;
#pragma unroll
        for (int ks = 0; ks < 4; ++ks) {
            short8 aw = *(const short8*)(wzA + (((t * 4 + ks) << 9) + (lane << 3)));
            C = __builtin_amdgcn_mfma_f32_32x32x16_bf16(aw, by[ks], C, 0, 0, 0);
        }
#pragma unroll
        for (int w = 0; w < 4; ++w) {
            f32x4 wb = *(const f32x4*)(wzb + t * 32 + w * 8 + hl * 4);
#pragma unroll
            for (int r = 0; r < 4; ++r) {
                int o = t * 32 + w * 8 + hl * 4 + r;
                size_t base = (size_t)o * HWN + tok;
                ob[base] = C[w * 4 + r] * linv + wb[r] + xb[base];
            }
        }
    }
}

extern "C" void kernel_launch(void* const* d_in, const int* in_sizes, int n_in,
                              void* d_out, int out_size, void* d_ws, size_t ws_size,
                              hipStream_t stream) {
    const float* x    = (const float*)d_in[0];
    const float* mb   = (const float*)d_in[1];
    const float* phiw = (const float*)d_in[2];
    const float* phib = (const float*)d_in[3];
    const float* gnw  = (const float*)d_in[4];
    const float* gnb  = (const float*)d_in[5];
    const float* wzw  = (const float*)d_in[6];
    const float* wzb  = (const float*)d_in[7];

    const int B = in_sizes[0] / (CCH * HWN);  // 10
    const int nstat = B * 256;                // 8 partial blocks per (b,g)

    // zero the atomic-sum region (float idx 36864..37504 of ws)
    hipMemsetAsync((char*)d_ws + 36864 * 4, 0, 640 * 4, stream);
    prep_stats_kernel<<<nstat + 288, 256, 0, stream>>>(x, mb, phiw, wzw,
                                                       (ushort*)d_ws, nstat);
    main_mfma<<<B * 128, 256, 0, stream>>>(x, (const ushort*)d_ws,
                                           phib, gnw, gnb, wzb, (float*)d_out);
}